// Round 26
// baseline (128.723 us; speedup 1.0000x reference)
//
#include <hip/hip_runtime.h>
#include <hip/hip_bf16.h>

typedef unsigned short u16;
typedef unsigned int u32;
typedef __attribute__((ext_vector_type(8))) short bf16x8;
typedef __attribute__((ext_vector_type(8))) unsigned short u16x8;
typedef __attribute__((ext_vector_type(4))) float f32x4;
typedef __attribute__((ext_vector_type(4))) unsigned short u16x4;

static constexpr int TSEQ = 512;
static constexpr int NSEQ = 128;      // B*F
static constexpr int NTOK = NSEQ * TSEQ;

__device__ __forceinline__ float bf2f(u16 u) {
  u32 i = ((u32)u) << 16; float f; __builtin_memcpy(&f, &i, 4); return f;
}
__device__ __forceinline__ u16 f2bf(float f) {
  u32 u; __builtin_memcpy(&u, &f, 4);
  return (u16)((u + 0x7FFFu + ((u >> 16) & 1u)) >> 16);
}
__device__ __forceinline__ f32x4 mfma16(bf16x8 a, bf16x8 b, f32x4 c) {
  return __builtin_amdgcn_mfma_f32_16x16x32_bf16(a, b, c, 0, 0, 0);
}
__device__ __forceinline__ void gload_lds16(const u16* g, u16* l) {
  __builtin_amdgcn_global_load_lds((const __attribute__((address_space(1))) void*)g,
                                   (__attribute__((address_space(3))) void*)l, 16, 0, 0);
}
// gelu via hw rcp (1-ulp): avoids the ~9-inst precise-div sequence
__device__ __forceinline__ float gelu_t(float v) {
  float uu = 0.7978845608f * (v + 0.044715f * v * v * v);
  return v * __builtin_amdgcn_rcpf(1.f + __expf(-2.f * uu));
}

// -- K0: weight conversion + rope tables + W2 col-mean + collapsed y_proj mats --
__global__ void k0_prep(const float* __restrict__ Wqkv, const float* __restrict__ Wo,
                        const float* __restrict__ W1, const float* __restrict__ W2,
                        const float* __restrict__ b2,
                        const float* __restrict__ W_in, const float* __restrict__ b_in,
                        const float* __restrict__ Wout, const float* __restrict__ bout,
                        u16* __restrict__ Wqkv_b, u16* __restrict__ Wo_b,
                        u16* __restrict__ W1_b, float* __restrict__ cm,
                        float* __restrict__ b2m,
                        float* __restrict__ Wcomb, float* __restrict__ bcomb,
                        float* __restrict__ rc, float* __restrict__ rs) {
  int i = blockIdx.x * 256 + threadIdx.x;
  if (i < 49152) Wqkv_b[i] = f2bf(Wqkv[i]);
  if (i < 16384) Wo_b[i] = f2bf(Wo[i]);
  if (i < 65536) W1_b[i] = f2bf(W1[i]);
  if (i < 512) {           // cm[h] = mean_d W2[d,h]
    float s = 0.f;
    for (int d = 0; d < 128; ++d) s += W2[d * 512 + i];
    cm[i] = s * (1.f / 128.f);
  }
  if (i == 0) {
    float s = 0.f;
    for (int d = 0; d < 128; ++d) s += b2[d];
    *b2m = s * (1.f / 128.f);
  }
  if (i < 1024) {          // Wcomb[l][f] = sum_d Wout[l,d] * W_in[d,f]
    int l = i >> 5, f = i & 31;
    float s = 0.f;
    for (int d = 0; d < 128; ++d) s += Wout[l * 128 + d] * W_in[d * 32 + f];
    Wcomb[i] = s;
  }
  if (i < 32) {            // bcomb[l] = bout[l] + sum_d Wout[l,d] * b_in[d]
    float s = bout[i];
    for (int d = 0; d < 128; ++d) s += Wout[i * 128 + d] * b_in[d];
    bcomb[i] = s;
  }
  if (i < 8192) {
    int t = i >> 4, fi = i & 15;
    float inv = powf(10000.f, -(float)(2 * fi) / 32.f);
    float ang = (float)t * inv;
    rc[i] = cosf(ang); rs[i] = sinf(ang);
  }
}

// ---- fused embed + LN1 + RoPE + QKV GEMM (unchanged from r25) ----
__global__ __launch_bounds__(512, 4)
void embed_qkv(const float* __restrict__ x, const float* __restrict__ W_in,
               const float* __restrict__ b_in,
               const float* __restrict__ g1, const float* __restrict__ be1,
               const float* __restrict__ rc, const float* __restrict__ rs,
               const u16* __restrict__ Wqkv, const float* __restrict__ bqkv,
               u16* __restrict__ QKb, u16* __restrict__ Vb) {
  __shared__ u16 Aq[64 * 128];    // qk tile (rope'd), swizzled chunks
  __shared__ u16 Ah[64 * 128];    // h1 tile, swizzled chunks
  const int tid = threadIdx.x, l = tid & 63, w = tid >> 6;
  const int lr = l & 15, lg = l >> 4;
  const int m0 = blockIdx.x * 64;
  const int seq = m0 >> 9, f = seq & 31, b = seq >> 5, tbase = m0 & 511;

  { // ---- embed phase: 8 thr/token x 16 dims ----
    const int tok = tid >> 3, j = tid & 7, d0 = j * 16;
    const int t = tbase + tok;
    float xv = x[((b << 9) + t) * 32 + f];
    float hc[16], av[16];
    float s = 0.f, ss = 0.f;
    #pragma unroll
    for (int m = 0; m < 16; ++m) {
      float v = xv * W_in[(d0 + m) * 32 + f] + b_in[d0 + m];
      hc[m] = v; s += v; ss += v * v;
    }
    s += __shfl_xor(s, 1); ss += __shfl_xor(ss, 1);
    s += __shfl_xor(s, 2); ss += __shfl_xor(ss, 2);
    s += __shfl_xor(s, 4); ss += __shfl_xor(ss, 4);
    float mean = s * (1.f / 128.f);
    float var = ss * (1.f / 128.f) - mean * mean;
    float rstd = rsqrtf(var + 1e-5f);
    #pragma unroll
    for (int m = 0; m < 16; ++m)
      av[m] = (hc[m] - mean) * rstd * g1[d0 + m] + be1[d0 + m];
    // h1 -> Ah (swizzled), qk = rope(h1) -> Aq
    u16x8 ah0, ah1, aq0, aq1;
    #pragma unroll
    for (int m = 0; m < 8; ++m) { ah0[m] = f2bf(av[m]); ah1[m] = f2bf(av[8 + m]); }
    #pragma unroll
    for (int m = 0; m < 8; ++m) {     // rope pairs: d = d0 + 2m
      int i16 = ((d0 >> 1) + m) & 15;
      float c = rc[t * 16 + i16], sn = rs[t * 16 + i16];
      float re = av[2 * m] * c - av[2 * m + 1] * sn;
      float ro = av[2 * m] * sn + av[2 * m + 1] * c;
      if (m < 4) { aq0[2 * m] = f2bf(re); aq0[2 * m + 1] = f2bf(ro); }
      else { aq1[2 * (m - 4)] = f2bf(re); aq1[2 * (m - 4) + 1] = f2bf(ro); }
    }
    const int p0 = j * 2;
    const int s0 = p0 ^ (tok & 7), s1 = (p0 + 1) ^ (tok & 7);
    *(u16x8*)(Ah + (tok * 16 + s0) * 8) = ah0;
    *(u16x8*)(Ah + (tok * 16 + s1) * 8) = ah1;
    *(u16x8*)(Aq + (tok * 16 + s0) * 8) = aq0;
    *(u16x8*)(Aq + (tok * 16 + s1) * 8) = aq1;
  }
  __syncthreads();

  // ---- QKV GEMM phase: N-split waves, Wqkv read once/block ----
  #pragma unroll 1
  for (int ph = 0; ph < 3; ++ph) {
    const u16* As = (ph == 2) ? Ah : Aq;
    const int wrow = ph * 128 + w * 16;               // wave's 16 W-rows (out cols)
    const u16* wr = Wqkv + (size_t)(wrow + lr) * 128 + lg * 8;
    bf16x8 wf0 = *(const bf16x8*)(wr);
    bf16x8 wf1 = *(const bf16x8*)(wr + 32);
    bf16x8 wf2 = *(const bf16x8*)(wr + 64);
    bf16x8 wf3 = *(const bf16x8*)(wr + 96);
    f32x4 bs = *(const f32x4*)(bqkv + wrow + lg * 4);
    u16* C = (ph == 2) ? Vb : QKb;
    const int ldc = (ph == 2) ? 128 : 256;
    const int ccol = ((ph == 2) ? 0 : ph * 128) + w * 16 + lg * 4;
    #pragma unroll
    for (int tt = 0; tt < 4; ++tt) {
      const int tok = tt * 16 + lr;
      const u16* ar = As + (tok * 16) * 8;
      f32x4 a0 = mfma16(wf0, *(const bf16x8*)(ar + ((lg ^ (lr & 7)) << 3)),
                        (f32x4){0.f, 0.f, 0.f, 0.f});
      a0 = mfma16(wf1, *(const bf16x8*)(ar + (((4 + lg) ^ (lr & 7)) << 3)), a0);
      f32x4 a1 = mfma16(wf2, *(const bf16x8*)(ar + (((8 + lg) ^ (lr & 7)) << 3)),
                        (f32x4){0.f, 0.f, 0.f, 0.f});
      a1 = mfma16(wf3, *(const bf16x8*)(ar + (((12 + lg) ^ (lr & 7)) << 3)), a1);
      f32x4 a = a0 + a1;
      u16x4 qv;
      #pragma unroll
      for (int r = 0; r < 4; ++r) qv[r] = f2bf(a[r] + bs[r]);
      *(u16x4*)(C + (size_t)(m0 + tok) * ldc + ccol) = qv;
    }
    __builtin_amdgcn_sched_barrier(0);
  }
}

// ---- fused Wo+LN+FFN v6: 32-token / 256-thread / 4-wave blocks (2048 blocks
// = 8 blocks/CU): finer packing (no exact-fit straggler round), barrier groups
// of 4 waves. Wave owns 32 Wo cols (2 halves); FFN 8 passes x 16 hid rows.
__global__ __launch_bounds__(256, 4)
void wo_ln_ffn(const u16* __restrict__ OB, const u16* __restrict__ Wo_b,
               const float* __restrict__ bo,
               const float* __restrict__ x, const float* __restrict__ W_in,
               const float* __restrict__ b_in,
               const float* __restrict__ g2, const float* __restrict__ be2,
               const u16* __restrict__ W1b, const float* __restrict__ b1,
               const float* __restrict__ cm, const float* __restrict__ b2m,
               float* __restrict__ yout) {
  __shared__ u16 Buf[32 * 136];    // phase 1: At[32][128] swizzled; phase 2: Ht[32][136]
  __shared__ float Sm[32 * 5], Sq[32 * 5];
  __shared__ float Yp[32 * 5];
  __shared__ float Hm[32];
  __shared__ float Xs[32];
  const int tid = threadIdx.x, l = tid & 63, w = tid >> 6;   // w: 0..3
  const int lr = l & 15, lg = l >> 4;
  const int m0 = blockIdx.x * 32;
  const int seq = m0 >> 9, f = seq & 31, b = seq >> 5, tbase = m0 & 511;
  const int wb = __builtin_amdgcn_readfirstlane(tid & 0xC0);

  #pragma unroll
  for (int it = 0; it < 2; ++it) {
    int ci = it * 256 + tid;
    int row = ci >> 4, p = ci & 15;
    gload_lds16(OB + (size_t)(m0 + row) * 128 + ((p ^ (row & 7)) << 3),
                Buf + (size_t)(it * 256 + wb) * 8);
  }
  if (tid < 32) Xs[tid] = x[((b << 9) + tbase + tid) * 32 + f];
  __syncthreads();

  // --- Wo GEMM: wave owns cols [w*32, w*32+32) in 2 halves; residual recompute ---
  f32x4 hvs[2][2];                      // [ch][tt]
  #pragma unroll
  for (int ch = 0; ch < 2; ++ch) {
    const int wrow = w * 32 + ch * 16;
    const u16* wr0 = Wo_b + (size_t)(wrow + lr) * 128 + lg * 8;
    bf16x8 wf0 = *(const bf16x8*)(wr0);
    bf16x8 wf1 = *(const bf16x8*)(wr0 + 32);
    bf16x8 wf2 = *(const bf16x8*)(wr0 + 64);
    bf16x8 wf3 = *(const bf16x8*)(wr0 + 96);
    f32x4 bs = *(const f32x4*)(bo + wrow + lg * 4);
    f32x4 winc, binc;
    #pragma unroll
    for (int r = 0; r < 4; ++r) {
      winc[r] = W_in[(wrow + lg * 4 + r) * 32 + f];
      binc[r] = b_in[wrow + lg * 4 + r];
    }
    #pragma unroll
    for (int tt = 0; tt < 2; ++tt) {
      const int tok = tt * 16 + lr;
      const u16* ar = Buf + (tok * 16) * 8;
      f32x4 a0 = mfma16(wf0, *(const bf16x8*)(ar + ((lg ^ (lr & 7)) << 3)),
                        (f32x4){0.f, 0.f, 0.f, 0.f});
      a0 = mfma16(wf1, *(const bf16x8*)(ar + (((4 + lg) ^ (lr & 7)) << 3)), a0);
      f32x4 a1 = mfma16(wf2, *(const bf16x8*)(ar + (((8 + lg) ^ (lr & 7)) << 3)),
                        (f32x4){0.f, 0.f, 0.f, 0.f});
      a1 = mfma16(wf3, *(const bf16x8*)(ar + (((12 + lg) ^ (lr & 7)) << 3)), a1);
      f32x4 a = a0 + a1;
      float xv = Xs[tok];
      #pragma unroll
      for (int r = 0; r < 4; ++r)
        hvs[ch][tt][r] = a[r] + bs[r] + (xv * winc[r] + binc[r]);
    }
  }
  // LN partials: per-token sum over this wave's 32 cols (2 ch x 4 lg x 4 r)
  #pragma unroll
  for (int tt = 0; tt < 2; ++tt) {
    float pm = 0.f, pq = 0.f;
    #pragma unroll
    for (int ch = 0; ch < 2; ++ch)
      #pragma unroll
      for (int r = 0; r < 4; ++r) {
        float v = hvs[ch][tt][r];
        pm += v; pq += v * v;
      }
    pm += __shfl_xor(pm, 16); pq += __shfl_xor(pq, 16);
    pm += __shfl_xor(pm, 32); pq += __shfl_xor(pq, 32);
    if (lg == 0) { Sm[(tt * 16 + lr) * 5 + w] = pm; Sq[(tt * 16 + lr) * 5 + w] = pq; }
  }
  __syncthreads();   // all At reads done -> safe to overlay Ht
  #pragma unroll
  for (int tt = 0; tt < 2; ++tt) {
    const int tok = tt * 16 + lr;
    float s = 0.f, q = 0.f;
    #pragma unroll
    for (int ww = 0; ww < 4; ++ww) { s += Sm[tok * 5 + ww]; q += Sq[tok * 5 + ww]; }
    float mean = s * (1.f / 128.f);
    float var = q * (1.f / 128.f) - mean * mean;
    float rstd = rsqrtf(var + 1e-5f);
    if (w == 0 && lg == 0) Hm[tok] = mean;
    #pragma unroll
    for (int ch = 0; ch < 2; ++ch) {
      const int wrow = w * 32 + ch * 16;
      f32x4 gm = *(const f32x4*)(g2 + wrow + lg * 4);
      f32x4 bt = *(const f32x4*)(be2 + wrow + lg * 4);
      u16x4 qv;
      #pragma unroll
      for (int r = 0; r < 4; ++r)
        qv[r] = f2bf((hvs[ch][tt][r] - mean) * rstd * gm[r] + bt[r]);
      *(u16x4*)(Buf + tok * 136 + wrow + lg * 4) = qv;
    }
  }
  __syncthreads();

  // --- FFN: wave owns 16 hidden rows per pass, 8 passes; split 2+2 chains ---
  float yacc[2] = {0.f, 0.f};
  #pragma unroll 1
  for (int p = 0; p < 8; ++p) {
    const int hb = (p * 4 + w) * 16;
    const u16* wr = W1b + (size_t)(hb + lr) * 128 + lg * 8;
    bf16x8 wf0 = *(const bf16x8*)(wr);
    bf16x8 wf1 = *(const bf16x8*)(wr + 32);
    bf16x8 wf2 = *(const bf16x8*)(wr + 64);
    bf16x8 wf3 = *(const bf16x8*)(wr + 96);
    f32x4 cmv = *(const f32x4*)(cm + hb + lg * 4);
    f32x4 bsv = *(const f32x4*)(b1 + hb + lg * 4);
    #pragma unroll
    for (int tt = 0; tt < 2; ++tt) {
      const u16* ar = Buf + (tt * 16 + lr) * 136 + lg * 8;
      f32x4 a0 = mfma16(wf0, *(const bf16x8*)(ar), (f32x4){0.f, 0.f, 0.f, 0.f});
      a0 = mfma16(wf1, *(const bf16x8*)(ar + 32), a0);
      f32x4 a1 = mfma16(wf2, *(const bf16x8*)(ar + 64), (f32x4){0.f, 0.f, 0.f, 0.f});
      a1 = mfma16(wf3, *(const bf16x8*)(ar + 96), a1);
      f32x4 a = a0 + a1;
      #pragma unroll
      for (int r = 0; r < 4; ++r)
        yacc[tt] += cmv[r] * gelu_t(a[r] + bsv[r]);
    }
    __builtin_amdgcn_sched_barrier(0);
  }

  #pragma unroll
  for (int tt = 0; tt < 2; ++tt) {
    float p = yacc[tt];
    p += __shfl_xor(p, 16);
    p += __shfl_xor(p, 32);
    if (lg == 0) Yp[(tt * 16 + lr) * 5 + w] = p;
  }
  __syncthreads();
  if (tid < 32) {
    float s = 0.f;
    #pragma unroll
    for (int ww = 0; ww < 4; ++ww) s += Yp[tid * 5 + ww];
    yout[m0 + tid] = Hm[tid] + b2m[0] + s;
  }
}

// ---------------- MFMA windowed attention (unchanged) ----------------
__global__ __launch_bounds__(256, 4)
void attn_mfma(const u16* __restrict__ QK, const u16* __restrict__ V, u16* __restrict__ O) {
  __shared__ u16 Ks[192 * 32];
  __shared__ u16 Vt[32 * 192];
  __shared__ u16 Pl[4][16 * 96];
  typedef __attribute__((ext_vector_type(2))) unsigned int u32x2;
  const int qstart = blockIdx.x * 128, seq = blockIdx.y, h = blockIdx.z;
  const int tid = threadIdx.x, w = tid >> 6, l = tid & 63;
  const int lr = l & 15, lg = l >> 4;
  const size_t base = (size_t)seq * TSEQ;

  #pragma unroll
  for (int it = 0; it < 3; ++it) {
    int idx = it * 256 + tid;
    int kl = idx >> 2, c = idx & 3;
    int kg = qstart - 64 + kl; if (kg < 0) kg = 0;
    bf16x8 kv = *(const bf16x8*)(QK + (base + kg) * 256 + 128 + h * 32 + c * 8);
    int pc = c ^ ((kl >> 1) & 3);
    *(bf16x8*)(Ks + kl * 32 + pc * 8) = kv;
    bf16x8 vv = *(const bf16x8*)(V + (base + kg) * 128 + h * 32 + c * 8);
    #pragma unroll
    for (int j = 0; j < 8; ++j) {
      int hd = c * 8 + j;
      int f = ((hd & 7) ^ (hd >> 3)) & 7;
      Vt[hd * 192 + (((kl >> 3) ^ f) * 8) + (kl & 7)] = (u16)vv[j];
    }
  }
  __syncthreads();

  const float scale = 0.17677669529663687f;
  for (int qt = 0; qt < 2; ++qt) {
    const int klbase = (w * 2 + qt) * 16;
    const int t0 = qstart + klbase;
    bf16x8 qf = *(const bf16x8*)(QK + (base + t0 + lr) * 256 + h * 32 + lg * 8);
    f32x4 s[5];
    #pragma unroll
    for (int kt = 0; kt < 5; ++kt) {
      int key = klbase + kt * 16 + lr;
      int pc = lg ^ ((key >> 1) & 3);
      bf16x8 kf = *(const bf16x8*)(Ks + key * 32 + pc * 8);
      s[kt] = mfma16(kf, qf, (f32x4){0.f, 0.f, 0.f, 0.f});
    }
    float m = -1e30f;
    #pragma unroll
    for (int kt = 0; kt < 5; ++kt)
      #pragma unroll
      for (int r = 0; r < 4; ++r) {
        int kl = kt * 16 + lg * 4 + r;
        bool valid = (kl >= lr) && (kl <= lr + 64) && (kl >= 64 - t0);
        float sv = valid ? s[kt][r] * scale : -1e30f;
        s[kt][r] = sv;
        m = fmaxf(m, sv);
      }
    m = fmaxf(m, __shfl_xor(m, 16));
    m = fmaxf(m, __shfl_xor(m, 32));
    float sum = 0.f;
    #pragma unroll
    for (int kt = 0; kt < 5; ++kt)
      #pragma unroll
      for (int r = 0; r < 4; ++r) { float p = __expf(s[kt][r] - m); s[kt][r] = p; sum += p; }
    sum += __shfl_xor(sum, 16);
    sum += __shfl_xor(sum, 32);
    float rinv = 1.f / sum;
    u16* P = Pl[w];
    #pragma unroll
    for (int kt = 0; kt < 5; ++kt) {
      u32 lo = (u32)f2bf(s[kt][0] * rinv) | ((u32)f2bf(s[kt][1] * rinv) << 16);
      u32 hi = (u32)f2bf(s[kt][2] * rinv) | ((u32)f2bf(s[kt][3] * rinv) << 16);
      int u = 2 * kt + (lg >> 1);
      int up = (u & ~3) | ((u & 3) ^ (lr & 3));
      *(u32x2*)(P + lr * 96 + up * 8 + (lg & 1) * 4) = (u32x2){lo, hi};
    }
    {
      int u = 10 + (lg >> 1);
      int up = (u & ~3) | ((u & 3) ^ (lr & 3));
      *(u32x2*)(P + lr * 96 + up * 8 + (lg & 1) * 4) = (u32x2){0u, 0u};
    }
    f32x4 acc[2] = {{0.f,0.f,0.f,0.f},{0.f,0.f,0.f,0.f}};
    #pragma unroll
    for (int c = 0; c < 3; ++c) {
      int u = 4 * c + (lg ^ (lr & 3));
      bf16x8 pf = *(const bf16x8*)(P + lr * 96 + u * 8);
      #pragma unroll
      for (int n = 0; n < 2; ++n) {
        int hd = n * 16 + lr;
        int f = ((hd & 7) ^ (hd >> 3)) & 7;
        int uv = (klbase >> 3) + 4 * c + lg; if (uv > 23) uv = 23;
        bf16x8 vf = *(const bf16x8*)(Vt + hd * 192 + ((uv ^ f) * 8));
        acc[n] = mfma16(pf, vf, acc[n]);
      }
    }
    #pragma unroll
    for (int n = 0; n < 2; ++n)
      #pragma unroll
      for (int r = 0; r < 4; ++r)
        O[(base + t0 + lg * 4 + r) * 128 + h * 32 + n * 16 + lr] = f2bf(acc[n][r]);
  }
}

// ---- K7 v2: out = x + yout_perm + x@Wcomb^T + bcomb (Wcomb = Wout·W_in) ----
__global__ void k7_out(const float* __restrict__ x, const float* __restrict__ Wcomb,
                       const float* __restrict__ bcomb, const float* __restrict__ yout,
                       float* __restrict__ out) {
  __shared__ float Wc[32 * 33];
  __shared__ float bc[32];
  const int tid = threadIdx.x;
  for (int i = tid; i < 1024; i += 256) Wc[(i >> 5) * 33 + (i & 31)] = Wcomb[i];
  if (tid < 32) bc[tid] = bcomb[tid];
  __syncthreads();
  const int p = blockIdx.x * 8 + (tid >> 5);
  const int l = tid & 31;
  const int bb = p >> 9, t = p & 511;
  float xv = x[(size_t)p * 32 + l];
  float acc = bc[l];
  #pragma unroll
  for (int ff = 0; ff < 32; ++ff) {
    float xf = __shfl(xv, ff, 32);
    acc += xf * Wc[l * 33 + ff];
  }
  float yo = yout[((bb * 32 + l) << 9) + t];
  out[(size_t)p * 32 + l] = xv + yo + acc;
}

extern "C" void kernel_launch(void* const* d_in, const int* in_sizes, int n_in,
                              void* d_out, int out_size, void* d_ws, size_t ws_size,
                              hipStream_t stream) {
  const float* x    = (const float*)d_in[0];
  const float* W_in = (const float*)d_in[1];
  const float* b_in = (const float*)d_in[2];
  const float* g1   = (const float*)d_in[3];
  const float* be1  = (const float*)d_in[4];
  const float* g2   = (const float*)d_in[5];
  const float* be2  = (const float*)d_in[6];
  const float* Wqkv = (const float*)d_in[7];
  const float* bqkv = (const float*)d_in[8];
  const float* Wo   = (const float*)d_in[9];
  const float* bo   = (const float*)d_in[10];
  const float* W1   = (const float*)d_in[11];
  const float* b1   = (const float*)d_in[12];
  const float* W2   = (const float*)d_in[13];
  const float* b2   = (const float*)d_in[14];
  const float* Wout = (const float*)d_in[15];
  const float* bout = (const float*)d_in[16];
  float* out = (float*)d_out;

  char* ws = (char*)d_ws;
  size_t off = 0;
  auto alloc = [&](size_t bytes) -> void* {
    void* p = ws + off; off += (bytes + 1023) & ~(size_t)1023; return p;
  };
  float* rc     = (float*)alloc(512 * 16 * 4);
  float* rs     = (float*)alloc(512 * 16 * 4);
  u16* Wqkv_b   = (u16*)alloc(49152 * 2);
  u16* Wo_b     = (u16*)alloc(16384 * 2);
  u16* W1_b     = (u16*)alloc(65536 * 2);
  float* cm     = (float*)alloc(512 * 4);
  float* b2m    = (float*)alloc(4);
  float* Wcomb  = (float*)alloc(1024 * 4);
  float* bcomb  = (float*)alloc(32 * 4);
  float* yout   = (float*)alloc((size_t)NTOK * 4);
  u16* obuf     = (u16*)alloc((size_t)NTOK * 128 * 2);
  u16* QKb      = (u16*)alloc((size_t)NTOK * 256 * 2);
  u16* Vb       = (u16*)alloc((size_t)NTOK * 128 * 2);

  k0_prep<<<dim3(256), dim3(256), 0, stream>>>(Wqkv, Wo, W1, W2, b2,
                                               W_in, b_in, Wout, bout,
                                               Wqkv_b, Wo_b, W1_b, cm, b2m,
                                               Wcomb, bcomb, rc, rs);
  // embed + LN1 + RoPE + QKV in one dispatch; h1/qk/hcf never hit HBM
  embed_qkv<<<dim3(1024), dim3(512), 0, stream>>>(x, W_in, b_in, g1, be1, rc, rs,
                                                  Wqkv_b, bqkv, QKb, Vb);
  attn_mfma<<<dim3(4, 128, 4), dim3(256), 0, stream>>>(QKb, Vb, obuf);
  // residual recomputed in-kernel; yout = h2mean + b2mean + cm·gelu(W1·h3+b1)
  wo_ln_ffn<<<dim3(2048), dim3(256), 0, stream>>>(obuf, Wo_b, bo, x, W_in, b_in,
                                                  g2, be2, W1_b, b1, cm, b2m, yout);
  k7_out<<<dim3(256), dim3(256), 0, stream>>>(x, Wcomb, bcomb, yout, out);
}

// Round 27
// 112.655 us; speedup vs baseline: 1.1426x; 1.1426x over previous
//
#include <hip/hip_runtime.h>
#include <hip/hip_bf16.h>

typedef unsigned short u16;
typedef unsigned int u32;
typedef __attribute__((ext_vector_type(8))) short bf16x8;
typedef __attribute__((ext_vector_type(8))) unsigned short u16x8;
typedef __attribute__((ext_vector_type(4))) float f32x4;
typedef __attribute__((ext_vector_type(4))) unsigned short u16x4;

static constexpr int TSEQ = 512;
static constexpr int NSEQ = 128;      // B*F
static constexpr int NTOK = NSEQ * TSEQ;

__device__ __forceinline__ float bf2f(u16 u) {
  u32 i = ((u32)u) << 16; float f; __builtin_memcpy(&f, &i, 4); return f;
}
__device__ __forceinline__ u16 f2bf(float f) {
  u32 u; __builtin_memcpy(&u, &f, 4);
  return (u16)((u + 0x7FFFu + ((u >> 16) & 1u)) >> 16);
}
__device__ __forceinline__ f32x4 mfma16(bf16x8 a, bf16x8 b, f32x4 c) {
  return __builtin_amdgcn_mfma_f32_16x16x32_bf16(a, b, c, 0, 0, 0);
}
__device__ __forceinline__ void gload_lds16(const u16* g, u16* l) {
  __builtin_amdgcn_global_load_lds((const __attribute__((address_space(1))) void*)g,
                                   (__attribute__((address_space(3))) void*)l, 16, 0, 0);
}
// gelu via hw rcp (1-ulp): avoids the ~9-inst precise-div sequence
__device__ __forceinline__ float gelu_t(float v) {
  float uu = 0.7978845608f * (v + 0.044715f * v * v * v);
  return v * __builtin_amdgcn_rcpf(1.f + __expf(-2.f * uu));
}

// -- K0: weight conversion + rope tables + W2 col-mean + collapsed y_proj mats --
__global__ void k0_prep(const float* __restrict__ Wqkv, const float* __restrict__ Wo,
                        const float* __restrict__ W1, const float* __restrict__ W2,
                        const float* __restrict__ b2,
                        const float* __restrict__ W_in, const float* __restrict__ b_in,
                        const float* __restrict__ Wout, const float* __restrict__ bout,
                        u16* __restrict__ Wqkv_b, u16* __restrict__ Wo_b,
                        u16* __restrict__ W1_b, float* __restrict__ cm,
                        float* __restrict__ b2m,
                        float* __restrict__ Wcomb, float* __restrict__ bcomb,
                        float* __restrict__ rc, float* __restrict__ rs) {
  int i = blockIdx.x * 256 + threadIdx.x;
  if (i < 49152) Wqkv_b[i] = f2bf(Wqkv[i]);
  if (i < 16384) Wo_b[i] = f2bf(Wo[i]);
  if (i < 65536) W1_b[i] = f2bf(W1[i]);
  if (i < 512) {           // cm[h] = mean_d W2[d,h]
    float s = 0.f;
    for (int d = 0; d < 128; ++d) s += W2[d * 512 + i];
    cm[i] = s * (1.f / 128.f);
  }
  if (i == 0) {
    float s = 0.f;
    for (int d = 0; d < 128; ++d) s += b2[d];
    *b2m = s * (1.f / 128.f);
  }
  if (i < 1024) {          // Wcomb[l][f] = sum_d Wout[l,d] * W_in[d,f]
    int l = i >> 5, f = i & 31;
    float s = 0.f;
    for (int d = 0; d < 128; ++d) s += Wout[l * 128 + d] * W_in[d * 32 + f];
    Wcomb[i] = s;
  }
  if (i < 32) {            // bcomb[l] = bout[l] + sum_d Wout[l,d] * b_in[d]
    float s = bout[i];
    for (int d = 0; d < 128; ++d) s += Wout[i * 128 + d] * b_in[d];
    bcomb[i] = s;
  }
  if (i < 8192) {
    int t = i >> 4, fi = i & 15;
    float inv = powf(10000.f, -(float)(2 * fi) / 32.f);
    float ang = (float)t * inv;
    rc[i] = cosf(ang); rs[i] = sinf(ang);
  }
}

// ---- fused embed + LN1 + RoPE + QKV GEMM. hcf is NOT materialized (wo_ln_ffn
// recomputes the rank-1 embed); h1/qk live only in swizzled LDS tiles.
__global__ __launch_bounds__(512, 4)
void embed_qkv(const float* __restrict__ x, const float* __restrict__ W_in,
               const float* __restrict__ b_in,
               const float* __restrict__ g1, const float* __restrict__ be1,
               const float* __restrict__ rc, const float* __restrict__ rs,
               const u16* __restrict__ Wqkv, const float* __restrict__ bqkv,
               u16* __restrict__ QKb, u16* __restrict__ Vb) {
  __shared__ u16 Aq[64 * 128];    // qk tile (rope'd), swizzled chunks
  __shared__ u16 Ah[64 * 128];    // h1 tile, swizzled chunks
  const int tid = threadIdx.x, l = tid & 63, w = tid >> 6;
  const int lr = l & 15, lg = l >> 4;
  const int m0 = blockIdx.x * 64;
  const int seq = m0 >> 9, f = seq & 31, b = seq >> 5, tbase = m0 & 511;

  { // ---- embed phase: 8 thr/token x 16 dims ----
    const int tok = tid >> 3, j = tid & 7, d0 = j * 16;
    const int t = tbase + tok;
    float xv = x[((b << 9) + t) * 32 + f];
    float hc[16], av[16];
    float s = 0.f, ss = 0.f;
    #pragma unroll
    for (int m = 0; m < 16; ++m) {
      float v = xv * W_in[(d0 + m) * 32 + f] + b_in[d0 + m];
      hc[m] = v; s += v; ss += v * v;
    }
    s += __shfl_xor(s, 1); ss += __shfl_xor(ss, 1);
    s += __shfl_xor(s, 2); ss += __shfl_xor(ss, 2);
    s += __shfl_xor(s, 4); ss += __shfl_xor(ss, 4);
    float mean = s * (1.f / 128.f);
    float var = ss * (1.f / 128.f) - mean * mean;
    float rstd = rsqrtf(var + 1e-5f);
    #pragma unroll
    for (int m = 0; m < 16; ++m)
      av[m] = (hc[m] - mean) * rstd * g1[d0 + m] + be1[d0 + m];
    // h1 -> Ah (swizzled), qk = rope(h1) -> Aq
    u16x8 ah0, ah1, aq0, aq1;
    #pragma unroll
    for (int m = 0; m < 8; ++m) { ah0[m] = f2bf(av[m]); ah1[m] = f2bf(av[8 + m]); }
    #pragma unroll
    for (int m = 0; m < 8; ++m) {     // rope pairs: d = d0 + 2m
      int i16 = ((d0 >> 1) + m) & 15;
      float c = rc[t * 16 + i16], sn = rs[t * 16 + i16];
      float re = av[2 * m] * c - av[2 * m + 1] * sn;
      float ro = av[2 * m] * sn + av[2 * m + 1] * c;
      if (m < 4) { aq0[2 * m] = f2bf(re); aq0[2 * m + 1] = f2bf(ro); }
      else { aq1[2 * (m - 4)] = f2bf(re); aq1[2 * (m - 4) + 1] = f2bf(ro); }
    }
    const int p0 = j * 2;
    const int s0 = p0 ^ (tok & 7), s1 = (p0 + 1) ^ (tok & 7);
    *(u16x8*)(Ah + (tok * 16 + s0) * 8) = ah0;
    *(u16x8*)(Ah + (tok * 16 + s1) * 8) = ah1;
    *(u16x8*)(Aq + (tok * 16 + s0) * 8) = aq0;
    *(u16x8*)(Aq + (tok * 16 + s1) * 8) = aq1;
  }
  __syncthreads();

  // ---- QKV GEMM phase: N-split waves, Wqkv read once/block ----
  #pragma unroll 1
  for (int ph = 0; ph < 3; ++ph) {
    const u16* As = (ph == 2) ? Ah : Aq;
    const int wrow = ph * 128 + w * 16;               // wave's 16 W-rows (out cols)
    const u16* wr = Wqkv + (size_t)(wrow + lr) * 128 + lg * 8;
    bf16x8 wf0 = *(const bf16x8*)(wr);
    bf16x8 wf1 = *(const bf16x8*)(wr + 32);
    bf16x8 wf2 = *(const bf16x8*)(wr + 64);
    bf16x8 wf3 = *(const bf16x8*)(wr + 96);
    f32x4 bs = *(const f32x4*)(bqkv + wrow + lg * 4);
    u16* C = (ph == 2) ? Vb : QKb;
    const int ldc = (ph == 2) ? 128 : 256;
    const int ccol = ((ph == 2) ? 0 : ph * 128) + w * 16 + lg * 4;
    #pragma unroll
    for (int tt = 0; tt < 4; ++tt) {
      const int tok = tt * 16 + lr;
      const u16* ar = As + (tok * 16) * 8;
      f32x4 a0 = mfma16(wf0, *(const bf16x8*)(ar + ((lg ^ (lr & 7)) << 3)),
                        (f32x4){0.f, 0.f, 0.f, 0.f});
      a0 = mfma16(wf1, *(const bf16x8*)(ar + (((4 + lg) ^ (lr & 7)) << 3)), a0);
      f32x4 a1 = mfma16(wf2, *(const bf16x8*)(ar + (((8 + lg) ^ (lr & 7)) << 3)),
                        (f32x4){0.f, 0.f, 0.f, 0.f});
      a1 = mfma16(wf3, *(const bf16x8*)(ar + (((12 + lg) ^ (lr & 7)) << 3)), a1);
      f32x4 a = a0 + a1;
      u16x4 qv;
      #pragma unroll
      for (int r = 0; r < 4; ++r) qv[r] = f2bf(a[r] + bs[r]);
      *(u16x4*)(C + (size_t)(m0 + tok) * ldc + ccol) = qv;
    }
    __builtin_amdgcn_sched_barrier(0);
  }
}

// ---- fused Wo+LN+FFN v5 (r25 best): 64-token / 512-thread blocks; rcpf-gelu;
// Sm/Sq/Yp padded to stride 9 (conflict-free cross-wave LN). 32-token halving
// (r26) doubled per-block W traffic and regressed -- 64 tokens is the measured
// U-curve minimum (128:59us, 64:45.7us, 32:56.7us).
__global__ __launch_bounds__(512, 4)
void wo_ln_ffn(const u16* __restrict__ OB, const u16* __restrict__ Wo_b,
               const float* __restrict__ bo,
               const float* __restrict__ x, const float* __restrict__ W_in,
               const float* __restrict__ b_in,
               const float* __restrict__ g2, const float* __restrict__ be2,
               const u16* __restrict__ W1b, const float* __restrict__ b1,
               const float* __restrict__ cm, const float* __restrict__ b2m,
               float* __restrict__ yout) {
  __shared__ u16 Buf[64 * 136];    // phase 1: At[64][128] swizzled; phase 2: Ht[64][136]
  __shared__ float Sm[64 * 9], Sq[64 * 9];
  __shared__ float Yp[64 * 9];
  __shared__ float Hm[64];
  __shared__ float Xs[64];
  const int tid = threadIdx.x, l = tid & 63, w = tid >> 6;
  const int lr = l & 15, lg = l >> 4;
  const int m0 = blockIdx.x * 64;
  const int seq = m0 >> 9, f = seq & 31, b = seq >> 5, tbase = m0 & 511;
  const int wb = __builtin_amdgcn_readfirstlane(tid & 0x1C0);

  #pragma unroll
  for (int it = 0; it < 2; ++it) {
    int ci = it * 512 + tid;
    int row = ci >> 4, p = ci & 15;
    gload_lds16(OB + (size_t)(m0 + row) * 128 + ((p ^ (row & 7)) << 3),
                Buf + (size_t)(it * 512 + wb) * 8);
  }
  if (tid < 64) Xs[tid] = x[((b << 9) + tbase + tid) * 32 + f];
  __syncthreads();

  // --- Wo GEMM (N-split) + recomputed residual + LN ---
  const int wrow = w * 16;
  {
    const u16* wr0 = Wo_b + (size_t)(wrow + lr) * 128 + lg * 8;
    bf16x8 wf0 = *(const bf16x8*)(wr0);
    bf16x8 wf1 = *(const bf16x8*)(wr0 + 32);
    bf16x8 wf2 = *(const bf16x8*)(wr0 + 64);
    bf16x8 wf3 = *(const bf16x8*)(wr0 + 96);
    f32x4 bs = *(const f32x4*)(bo + wrow + lg * 4);
    f32x4 winc, binc;                  // lane's 4 dims of W_in col f, b_in
    #pragma unroll
    for (int r = 0; r < 4; ++r) {
      winc[r] = W_in[(wrow + lg * 4 + r) * 32 + f];
      binc[r] = b_in[wrow + lg * 4 + r];
    }
    f32x4 hv[4];
    #pragma unroll
    for (int tt = 0; tt < 4; ++tt) {
      const int tok = tt * 16 + lr;
      const u16* ar = Buf + (tok * 16) * 8;
      f32x4 a0 = mfma16(wf0, *(const bf16x8*)(ar + ((lg ^ (lr & 7)) << 3)),
                        (f32x4){0.f, 0.f, 0.f, 0.f});
      a0 = mfma16(wf1, *(const bf16x8*)(ar + (((4 + lg) ^ (lr & 7)) << 3)), a0);
      f32x4 a1 = mfma16(wf2, *(const bf16x8*)(ar + (((8 + lg) ^ (lr & 7)) << 3)),
                        (f32x4){0.f, 0.f, 0.f, 0.f});
      a1 = mfma16(wf3, *(const bf16x8*)(ar + (((12 + lg) ^ (lr & 7)) << 3)), a1);
      f32x4 a = a0 + a1;
      float xv = Xs[tok];
      #pragma unroll
      for (int r = 0; r < 4; ++r)
        hv[tt][r] = a[r] + bs[r] + (xv * winc[r] + binc[r]);
    }
    #pragma unroll
    for (int tt = 0; tt < 4; ++tt) {
      float psm = hv[tt][0] + hv[tt][1] + hv[tt][2] + hv[tt][3];
      float psq = hv[tt][0] * hv[tt][0] + hv[tt][1] * hv[tt][1]
                + hv[tt][2] * hv[tt][2] + hv[tt][3] * hv[tt][3];
      psm += __shfl_xor(psm, 16); psq += __shfl_xor(psq, 16);
      psm += __shfl_xor(psm, 32); psq += __shfl_xor(psq, 32);
      if (lg == 0) { Sm[(tt * 16 + lr) * 9 + w] = psm; Sq[(tt * 16 + lr) * 9 + w] = psq; }
    }
    __syncthreads();   // also guarantees all At reads done before Ht overlay
    f32x4 gm = *(const f32x4*)(g2 + wrow + lg * 4);
    f32x4 bt = *(const f32x4*)(be2 + wrow + lg * 4);
    #pragma unroll
    for (int tt = 0; tt < 4; ++tt) {
      const int tok = tt * 16 + lr;
      float s = 0.f, q = 0.f;
      #pragma unroll
      for (int ww = 0; ww < 8; ++ww) { s += Sm[tok * 9 + ww]; q += Sq[tok * 9 + ww]; }
      float mean = s * (1.f / 128.f);
      float var = q * (1.f / 128.f) - mean * mean;
      float rstd = rsqrtf(var + 1e-5f);
      if (w == 0 && lg == 0) Hm[tok] = mean;
      u16x4 qv;
      #pragma unroll
      for (int r = 0; r < 4; ++r)
        qv[r] = f2bf((hv[tt][r] - mean) * rstd * gm[r] + bt[r]);
      *(u16x4*)(Buf + tok * 136 + wrow + lg * 4) = qv;
    }
  }
  __syncthreads();

  // --- FFN: wave owns 16 hidden rows per pass, 4 passes; split 2+2 chains ---
  float yacc[4] = {0.f, 0.f, 0.f, 0.f};
  #pragma unroll 1
  for (int p = 0; p < 4; ++p) {
    const int hb = (p * 8 + w) * 16;
    const u16* wr = W1b + (size_t)(hb + lr) * 128 + lg * 8;
    bf16x8 wf0 = *(const bf16x8*)(wr);
    bf16x8 wf1 = *(const bf16x8*)(wr + 32);
    bf16x8 wf2 = *(const bf16x8*)(wr + 64);
    bf16x8 wf3 = *(const bf16x8*)(wr + 96);
    f32x4 cmv = *(const f32x4*)(cm + hb + lg * 4);
    f32x4 bsv = *(const f32x4*)(b1 + hb + lg * 4);
    #pragma unroll
    for (int tt = 0; tt < 4; ++tt) {
      const u16* ar = Buf + (tt * 16 + lr) * 136 + lg * 8;
      f32x4 a0 = mfma16(wf0, *(const bf16x8*)(ar), (f32x4){0.f, 0.f, 0.f, 0.f});
      a0 = mfma16(wf1, *(const bf16x8*)(ar + 32), a0);
      f32x4 a1 = mfma16(wf2, *(const bf16x8*)(ar + 64), (f32x4){0.f, 0.f, 0.f, 0.f});
      a1 = mfma16(wf3, *(const bf16x8*)(ar + 96), a1);
      f32x4 a = a0 + a1;
      #pragma unroll
      for (int r = 0; r < 4; ++r)
        yacc[tt] += cmv[r] * gelu_t(a[r] + bsv[r]);
    }
    __builtin_amdgcn_sched_barrier(0);
  }

  #pragma unroll
  for (int tt = 0; tt < 4; ++tt) {
    float p = yacc[tt];
    p += __shfl_xor(p, 16);
    p += __shfl_xor(p, 32);
    if (lg == 0) Yp[(tt * 16 + lr) * 9 + w] = p;
  }
  __syncthreads();
  if (tid < 64) {
    float s = 0.f;
    #pragma unroll
    for (int ww = 0; ww < 8; ++ww) s += Yp[tid * 9 + ww];
    yout[m0 + tid] = Hm[tid] + b2m[0] + s;
  }
}

// ---------------- MFMA windowed attention (unchanged) ----------------
__global__ __launch_bounds__(256, 4)
void attn_mfma(const u16* __restrict__ QK, const u16* __restrict__ V, u16* __restrict__ O) {
  __shared__ u16 Ks[192 * 32];
  __shared__ u16 Vt[32 * 192];
  __shared__ u16 Pl[4][16 * 96];
  typedef __attribute__((ext_vector_type(2))) unsigned int u32x2;
  const int qstart = blockIdx.x * 128, seq = blockIdx.y, h = blockIdx.z;
  const int tid = threadIdx.x, w = tid >> 6, l = tid & 63;
  const int lr = l & 15, lg = l >> 4;
  const size_t base = (size_t)seq * TSEQ;

  #pragma unroll
  for (int it = 0; it < 3; ++it) {
    int idx = it * 256 + tid;
    int kl = idx >> 2, c = idx & 3;
    int kg = qstart - 64 + kl; if (kg < 0) kg = 0;
    bf16x8 kv = *(const bf16x8*)(QK + (base + kg) * 256 + 128 + h * 32 + c * 8);
    int pc = c ^ ((kl >> 1) & 3);
    *(bf16x8*)(Ks + kl * 32 + pc * 8) = kv;
    bf16x8 vv = *(const bf16x8*)(V + (base + kg) * 128 + h * 32 + c * 8);
    #pragma unroll
    for (int j = 0; j < 8; ++j) {
      int hd = c * 8 + j;
      int f = ((hd & 7) ^ (hd >> 3)) & 7;
      Vt[hd * 192 + (((kl >> 3) ^ f) * 8) + (kl & 7)] = (u16)vv[j];
    }
  }
  __syncthreads();

  const float scale = 0.17677669529663687f;
  for (int qt = 0; qt < 2; ++qt) {
    const int klbase = (w * 2 + qt) * 16;
    const int t0 = qstart + klbase;
    bf16x8 qf = *(const bf16x8*)(QK + (base + t0 + lr) * 256 + h * 32 + lg * 8);
    f32x4 s[5];
    #pragma unroll
    for (int kt = 0; kt < 5; ++kt) {
      int key = klbase + kt * 16 + lr;
      int pc = lg ^ ((key >> 1) & 3);
      bf16x8 kf = *(const bf16x8*)(Ks + key * 32 + pc * 8);
      s[kt] = mfma16(kf, qf, (f32x4){0.f, 0.f, 0.f, 0.f});
    }
    float m = -1e30f;
    #pragma unroll
    for (int kt = 0; kt < 5; ++kt)
      #pragma unroll
      for (int r = 0; r < 4; ++r) {
        int kl = kt * 16 + lg * 4 + r;
        bool valid = (kl >= lr) && (kl <= lr + 64) && (kl >= 64 - t0);
        float sv = valid ? s[kt][r] * scale : -1e30f;
        s[kt][r] = sv;
        m = fmaxf(m, sv);
      }
    m = fmaxf(m, __shfl_xor(m, 16));
    m = fmaxf(m, __shfl_xor(m, 32));
    float sum = 0.f;
    #pragma unroll
    for (int kt = 0; kt < 5; ++kt)
      #pragma unroll
      for (int r = 0; r < 4; ++r) { float p = __expf(s[kt][r] - m); s[kt][r] = p; sum += p; }
    sum += __shfl_xor(sum, 16);
    sum += __shfl_xor(sum, 32);
    float rinv = 1.f / sum;
    u16* P = Pl[w];
    #pragma unroll
    for (int kt = 0; kt < 5; ++kt) {
      u32 lo = (u32)f2bf(s[kt][0] * rinv) | ((u32)f2bf(s[kt][1] * rinv) << 16);
      u32 hi = (u32)f2bf(s[kt][2] * rinv) | ((u32)f2bf(s[kt][3] * rinv) << 16);
      int u = 2 * kt + (lg >> 1);
      int up = (u & ~3) | ((u & 3) ^ (lr & 3));
      *(u32x2*)(P + lr * 96 + up * 8 + (lg & 1) * 4) = (u32x2){lo, hi};
    }
    {
      int u = 10 + (lg >> 1);
      int up = (u & ~3) | ((u & 3) ^ (lr & 3));
      *(u32x2*)(P + lr * 96 + up * 8 + (lg & 1) * 4) = (u32x2){0u, 0u};
    }
    f32x4 acc[2] = {{0.f,0.f,0.f,0.f},{0.f,0.f,0.f,0.f}};
    #pragma unroll
    for (int c = 0; c < 3; ++c) {
      int u = 4 * c + (lg ^ (lr & 3));
      bf16x8 pf = *(const bf16x8*)(P + lr * 96 + u * 8);
      #pragma unroll
      for (int n = 0; n < 2; ++n) {
        int hd = n * 16 + lr;
        int f = ((hd & 7) ^ (hd >> 3)) & 7;
        int uv = (klbase >> 3) + 4 * c + lg; if (uv > 23) uv = 23;
        bf16x8 vf = *(const bf16x8*)(Vt + hd * 192 + ((uv ^ f) * 8));
        acc[n] = mfma16(pf, vf, acc[n]);
      }
    }
    #pragma unroll
    for (int n = 0; n < 2; ++n)
      #pragma unroll
      for (int r = 0; r < 4; ++r)
        O[(base + t0 + lg * 4 + r) * 128 + h * 32 + n * 16 + lr] = f2bf(acc[n][r]);
  }
}

// ---- K7 v2: out = x + yout_perm + x@Wcomb^T + bcomb (Wcomb = Wout·W_in) ----
__global__ void k7_out(const float* __restrict__ x, const float* __restrict__ Wcomb,
                       const float* __restrict__ bcomb, const float* __restrict__ yout,
                       float* __restrict__ out) {
  __shared__ float Wc[32 * 33];
  __shared__ float bc[32];
  const int tid = threadIdx.x;
  for (int i = tid; i < 1024; i += 256) Wc[(i >> 5) * 33 + (i & 31)] = Wcomb[i];
  if (tid < 32) bc[tid] = bcomb[tid];
  __syncthreads();
  const int p = blockIdx.x * 8 + (tid >> 5);
  const int l = tid & 31;
  const int bb = p >> 9, t = p & 511;
  float xv = x[(size_t)p * 32 + l];
  float acc = bc[l];
  #pragma unroll
  for (int ff = 0; ff < 32; ++ff) {
    float xf = __shfl(xv, ff, 32);
    acc += xf * Wc[l * 33 + ff];
  }
  float yo = yout[((bb * 32 + l) << 9) + t];
  out[(size_t)p * 32 + l] = xv + yo + acc;
}

extern "C" void kernel_launch(void* const* d_in, const int* in_sizes, int n_in,
                              void* d_out, int out_size, void* d_ws, size_t ws_size,
                              hipStream_t stream) {
  const float* x    = (const float*)d_in[0];
  const float* W_in = (const float*)d_in[1];
  const float* b_in = (const float*)d_in[2];
  const float* g1   = (const float*)d_in[3];
  const float* be1  = (const float*)d_in[4];
  const float* g2   = (const float*)d_in[5];
  const float* be2  = (const float*)d_in[6];
  const float* Wqkv = (const float*)d_in[7];
  const float* bqkv = (const float*)d_in[8];
  const float* Wo   = (const float*)d_in[9];
  const float* bo   = (const float*)d_in[10];
  const float* W1   = (const float*)d_in[11];
  const float* b1   = (const float*)d_in[12];
  const float* W2   = (const float*)d_in[13];
  const float* b2   = (const float*)d_in[14];
  const float* Wout = (const float*)d_in[15];
  const float* bout = (const float*)d_in[16];
  float* out = (float*)d_out;

  char* ws = (char*)d_ws;
  size_t off = 0;
  auto alloc = [&](size_t bytes) -> void* {
    void* p = ws + off; off += (bytes + 1023) & ~(size_t)1023; return p;
  };
  float* rc     = (float*)alloc(512 * 16 * 4);
  float* rs     = (float*)alloc(512 * 16 * 4);
  u16* Wqkv_b   = (u16*)alloc(49152 * 2);
  u16* Wo_b     = (u16*)alloc(16384 * 2);
  u16* W1_b     = (u16*)alloc(65536 * 2);
  float* cm     = (float*)alloc(512 * 4);
  float* b2m    = (float*)alloc(4);
  float* Wcomb  = (float*)alloc(1024 * 4);
  float* bcomb  = (float*)alloc(32 * 4);
  float* yout   = (float*)alloc((size_t)NTOK * 4);
  u16* obuf     = (u16*)alloc((size_t)NTOK * 128 * 2);
  u16* QKb      = (u16*)alloc((size_t)NTOK * 256 * 2);
  u16* Vb       = (u16*)alloc((size_t)NTOK * 128 * 2);

  k0_prep<<<dim3(256), dim3(256), 0, stream>>>(Wqkv, Wo, W1, W2, b2,
                                               W_in, b_in, Wout, bout,
                                               Wqkv_b, Wo_b, W1_b, cm, b2m,
                                               Wcomb, bcomb, rc, rs);
  // embed + LN1 + RoPE + QKV in one dispatch; h1/qk/hcf never hit HBM
  embed_qkv<<<dim3(1024), dim3(512), 0, stream>>>(x, W_in, b_in, g1, be1, rc, rs,
                                                  Wqkv_b, bqkv, QKb, Vb);
  attn_mfma<<<dim3(4, 128, 4), dim3(256), 0, stream>>>(QKb, Vb, obuf);
  // residual recomputed in-kernel; yout = h2mean + b2mean + cm·gelu(W1·h3+b1)
  wo_ln_ffn<<<dim3(1024), dim3(512), 0, stream>>>(obuf, Wo_b, bo, x, W_in, b_in,
                                                  g2, be2, W1_b, b1, cm, b2m, yout);
  k7_out<<<dim3(256), dim3(256), 0, stream>>>(x, Wcomb, bcomb, yout, out);
}